// Round 3
// baseline (471.749 us; speedup 1.0000x reference)
//
#include <hip/hip_runtime.h>
#include <hip/hip_bf16.h>
#include <stdint.h>

// Problem constants
#define NPAIR 512      // B*C
#define LTOK  128      // L
#define DDIM  768      // D
#define HDIM  768      // H
#define K2    1536     // 2*D

typedef float f32x4 __attribute__((ext_vector_type(4)));
typedef short bf16x8 __attribute__((ext_vector_type(8)));

static __device__ __forceinline__ unsigned short f2bf(float f) {
    union { float f; uint32_t u; } v; v.f = f;
    uint32_t u = v.u;
    u += 0x7FFF + ((u >> 16) & 1);   // RNE
    return (unsigned short)(u >> 16);
}

typedef const __attribute__((address_space(1))) void* gas_t;
typedef __attribute__((address_space(3))) void* las_t;
static __device__ __forceinline__ void gld16(const void* g, void* l) {
    __builtin_amdgcn_global_load_lds((gas_t)g, (las_t)l, 16, 0, 0);
}

// ---------------------------------------------------------------------------
// Kernel 1: sim = C @ E^T (fp32), rowwise max + argmax.
// Grid (NPAIR, 2): block handles 64 context rows x all 128 entity cols.
// (2 blocks/pair -> 4 blocks/CU, fixes the 20%-occupancy latency bind.)
// WB: emits bf16 copies of context (own 64 rows) / entity (own row-half).
// ---------------------------------------------------------------------------
template<bool WB>
__global__ __launch_bounds__(256) void sim_max_kernel(
        const float* __restrict__ inp,
        float* __restrict__ dotmax, int* __restrict__ argmax,
        unsigned short* __restrict__ Cbf, unsigned short* __restrict__ Ebf)
{
    const int p  = blockIdx.x;
    const int hh = blockIdx.y;            // row-half: 0 or 1
    const int t  = threadIdx.x;
    const int tx = t & 15, ty = t >> 4;
    const float* Cbase = inp + (size_t)(2 * p) * LTOK * DDIM + (size_t)hh * 64 * DDIM;
    const float* Ebase = inp + (size_t)(2 * p + 1) * LTOK * DDIM;

    __shared__ float Ct[64][36];    // 9.2 KB
    __shared__ float Et[128][36];   // 18.4 KB

    float acc[4][8];
#pragma unroll
    for (int i = 0; i < 4; i++)
#pragma unroll
        for (int j = 0; j < 8; j++) acc[i][j] = 0.f;

    for (int kc = 0; kc < 24; ++kc) {
        const int k0 = kc * 32;
        // stage C: 64 rows x 32 k = 512 float4, 2/thread
#pragma unroll
        for (int q = 0; q < 2; ++q) {
            int f = q * 256 + t;
            int row = f >> 3, c4 = f & 7;
            f32x4 cv = *(const f32x4*)(Cbase + (size_t)row * DDIM + k0 + c4 * 4);
            *(f32x4*)&Ct[row][c4 * 4] = cv;
            if (WB) {
                uint2 cw;
                cw.x = (unsigned)f2bf(cv[0]) | ((unsigned)f2bf(cv[1]) << 16);
                cw.y = (unsigned)f2bf(cv[2]) | ((unsigned)f2bf(cv[3]) << 16);
                *(uint2*)(Cbf + ((size_t)p * LTOK + hh * 64 + row) * DDIM + k0 + c4 * 4) = cw;
            }
        }
        // stage E: 128 rows x 32 k = 1024 float4, 4/thread
#pragma unroll
        for (int q = 0; q < 4; ++q) {
            int f = q * 256 + t;
            int row = f >> 3, c4 = f & 7;
            f32x4 ev = *(const f32x4*)(Ebase + (size_t)row * DDIM + k0 + c4 * 4);
            *(f32x4*)&Et[row][c4 * 4] = ev;
            if (WB && (row >> 6) == hh) {   // write each entity row exactly once
                uint2 ew;
                ew.x = (unsigned)f2bf(ev[0]) | ((unsigned)f2bf(ev[1]) << 16);
                ew.y = (unsigned)f2bf(ev[2]) | ((unsigned)f2bf(ev[3]) << 16);
                *(uint2*)(Ebf + ((size_t)p * LTOK + row) * DDIM + k0 + c4 * 4) = ew;
            }
        }
        __syncthreads();
#pragma unroll
        for (int kk4 = 0; kk4 < 8; ++kk4) {
            f32x4 cr[4], er[8];
#pragma unroll
            for (int i = 0; i < 4; i++) cr[i] = *(const f32x4*)&Ct[ty + 16 * i][kk4 * 4];
#pragma unroll
            for (int j = 0; j < 8; j++) er[j] = *(const f32x4*)&Et[tx + 16 * j][kk4 * 4];
#pragma unroll
            for (int kk = 0; kk < 4; kk++)
#pragma unroll
                for (int i = 0; i < 4; i++)
#pragma unroll
                    for (int j = 0; j < 8; j++)
                        acc[i][j] = fmaf(cr[i][kk], er[j][kk], acc[i][j]);
        }
        __syncthreads();
    }

    // rowwise max + argmax (first/lowest index on ties)
#pragma unroll
    for (int i = 0; i < 4; i++) {
        float m = acc[i][0]; int mi = tx;
#pragma unroll
        for (int j = 1; j < 8; j++) {
            int c = tx + 16 * j;
            float v = acc[i][j];
            if (v > m || (v == m && c < mi)) { m = v; mi = c; }
        }
#pragma unroll
        for (int sft = 1; sft < 16; sft <<= 1) {
            float vo = __shfl_xor(m, sft);
            int   io = __shfl_xor(mi, sft);
            if (vo > m || (vo == m && io < mi)) { m = vo; mi = io; }
        }
        if (tx == 0) {
            int r = hh * 64 + ty + 16 * i;
            dotmax[(size_t)p * LTOK + r] = m;
            argmax[(size_t)p * LTOK + r] = mi;
        }
    }
}

// ---------------------------------------------------------------------------
// Kernel 2: W1 [1536,768] fp32 -> W1T [768][1536] bf16.
// Output-indexed: scattered 4B reads (L2-absorbed, W1 = 4.7MB), coalesced
// uint4 writes (8 bf16 per thread).
// ---------------------------------------------------------------------------
__global__ __launch_bounds__(256) void w1t_kernel(
        const float* __restrict__ W1, unsigned short* __restrict__ W1T)
{
    int idx = blockIdx.x * 256 + threadIdx.x;      // 147456 threads, 8 k each
    if (idx >= HDIM * K2 / 8) return;
    int c  = idx / (K2 / 8);
    int k0 = (idx % (K2 / 8)) * 8;
    unsigned short v[8];
#pragma unroll
    for (int q = 0; q < 8; q++) v[q] = f2bf(W1[(size_t)(k0 + q) * HDIM + c]);
    *(uint4*)(W1T + (size_t)c * K2 + k0) = *(const uint4*)v;
}

// ---------------------------------------------------------------------------
// Kernel 3: m97-style MFMA GEMM. Block = 1 pair (128 tokens) x 256 cols,
// grid (512, 3). 4 waves, wave tile 64x128, acc 4x8, BK=64 as 2x32-k panels.
// A (gathered, bf16) and B staged via global_load_lds width=16.
// ---------------------------------------------------------------------------
__global__ __launch_bounds__(256, 2) void mlp2_kernel(
        const unsigned short* __restrict__ Cbf,
        const unsigned short* __restrict__ Ebf,
        const unsigned short* __restrict__ W1T,
        const float* __restrict__ b1,
        const float* __restrict__ W2,
        const int* __restrict__ argmax,
        float* __restrict__ tokscore)
{
    const int p    = blockIdx.x;
    const int cbk  = blockIdx.y;           // 0..2, 256 cols each
    const int t    = threadIdx.x;
    const int wv   = t >> 6;
    const int lane = t & 63;
    const int s    = lane & 15, g = lane >> 4;
    const int wr   = wv >> 1, wc = wv & 1; // 64-row half, 128-col half

    __shared__ unsigned short Ald[2][128][32];   // 16 KB
    __shared__ unsigned short Bld[2][256][32];   // 32 KB
    __shared__ int am[128];

    if (t < 128) am[t] = argmax[p * LTOK + t];

    f32x4 acc[4][8];
#pragma unroll
    for (int i = 0; i < 4; i++)
#pragma unroll
        for (int j = 0; j < 8; j++) acc[i][j] = (f32x4){0.f, 0.f, 0.f, 0.f};

    const int rsub = lane >> 2;      // 0..15
    const int chk  = lane & 3;       // 16B chunk within 64B row

    for (int kc = 0; kc < 24; ++kc) {
        const int k0   = kc * 64;
        const bool ctx = (kc < 12);
        const int kloc = ctx ? k0 : (k0 - DDIM);

#pragma unroll
        for (int h = 0; h < 2; ++h)
#pragma unroll
            for (int n = 0; n < 4; ++n) {
                int c0  = (wv * 4 + n) * 16;
                int col = c0 + rsub;
                const unsigned short* src =
                    W1T + (size_t)(cbk * 256 + col) * K2 + k0 + h * 32 + chk * 8;
                gld16(src, &Bld[h][c0][0]);
            }
#pragma unroll
        for (int h = 0; h < 2; ++h)
#pragma unroll
            for (int n = 0; n < 2; ++n) {
                int r0 = (wv * 2 + n) * 16;
                int r  = r0 + rsub;
                const unsigned short* base = ctx
                    ? (Cbf + ((size_t)p * LTOK + r) * DDIM)
                    : (Ebf + ((size_t)p * LTOK + am[r]) * DDIM);
                gld16(base + kloc + h * 32 + chk * 8, &Ald[h][r0][0]);
            }
        __syncthreads();

#pragma unroll
        for (int h = 0; h < 2; ++h) {
            bf16x8 af[4], bfr[8];
#pragma unroll
            for (int i = 0; i < 4; ++i)
                af[i] = *(const bf16x8*)&Ald[h][wr * 64 + i * 16 + s][g * 8];
#pragma unroll
            for (int j = 0; j < 8; ++j)
                bfr[j] = *(const bf16x8*)&Bld[h][wc * 128 + j * 16 + s][g * 8];
#pragma unroll
            for (int i = 0; i < 4; ++i)
#pragma unroll
                for (int j = 0; j < 8; ++j)
                    acc[i][j] = __builtin_amdgcn_mfma_f32_16x16x32_bf16(af[i], bfr[j], acc[i][j], 0, 0, 0);
        }
        __syncthreads();
    }

    // epilogue: relu(acc + b1) . W2, reduce over 16 col-lanes, atomic per token
    float w2v[8], b1v[8];
#pragma unroll
    for (int j = 0; j < 8; j++) {
        int col = cbk * 256 + wc * 128 + j * 16 + s;
        w2v[j] = W2[col];
        b1v[j] = b1[col];
    }
    float ssum[4][4];
#pragma unroll
    for (int i = 0; i < 4; i++)
#pragma unroll
        for (int r = 0; r < 4; r++) ssum[i][r] = 0.f;
#pragma unroll
    for (int i = 0; i < 4; i++)
#pragma unroll
        for (int j = 0; j < 8; j++)
#pragma unroll
            for (int r = 0; r < 4; r++) {
                float h = acc[i][j][r] + b1v[j];
                h = h > 0.f ? h : 0.f;
                ssum[i][r] = fmaf(h, w2v[j], ssum[i][r]);
            }
#pragma unroll
    for (int sft = 1; sft < 16; sft <<= 1)
#pragma unroll
        for (int i = 0; i < 4; i++)
#pragma unroll
            for (int r = 0; r < 4; r++) ssum[i][r] += __shfl_xor(ssum[i][r], sft);
    if (s == 0) {
#pragma unroll
        for (int i = 0; i < 4; i++)
#pragma unroll
            for (int r = 0; r < 4; r++)
                atomicAdd(&tokscore[p * LTOK + wr * 64 + i * 16 + g * 4 + r], ssum[i][r]);
    }
}

// ---------------------------------------------------------------------------
// Kernel 3 (fallback, ws too small): fused gather + MFMA GEMM from fp32
// ---------------------------------------------------------------------------
__global__ __launch_bounds__(256, 2) void mlp_kernel(
        const float* __restrict__ inp,
        const unsigned short* __restrict__ W1T,
        const float* __restrict__ b1,
        const float* __restrict__ W2,
        const int* __restrict__ argmax,
        float* __restrict__ tokscore)
{
    const int tile = blockIdx.x;
    const int cb   = blockIdx.y;
    const int t    = threadIdx.x;
    const int wv   = t >> 6;
    const int lane = t & 63;
    const int s    = lane & 15, g = lane >> 4;

    __shared__ unsigned short At[64][32];
    __shared__ unsigned short Bt[384][32];
    __shared__ int am[64];

    if (t < 64) am[t] = argmax[tile * 64 + t];
    __syncthreads();

    f32x4 acc[4][6];
#pragma unroll
    for (int i = 0; i < 4; i++)
#pragma unroll
        for (int j = 0; j < 6; j++) acc[i][j] = (f32x4){0.f, 0.f, 0.f, 0.f};

    for (int kc = 0; kc < 48; ++kc) {
        const int k0  = kc * 32;
        const int sel = (kc >= 24) ? 1 : 0;
        const int kloc = k0 - sel * DDIM;
#pragma unroll
        for (int q = 0; q < 2; ++q) {
            int f = q * 256 + t;
            int row = f >> 3, c4 = f & 7;
            int token = tile * 64 + row;
            int pp = token >> 7;
            int lsel = sel ? am[row] : (token & 127);
            const float* src = inp + ((size_t)(2 * pp + sel) * LTOK + lsel) * DDIM + kloc + c4 * 4;
            f32x4 v = *(const f32x4*)src;
            unsigned int w0 = (unsigned)f2bf(v[0]) | ((unsigned)f2bf(v[1]) << 16);
            unsigned int w1 = (unsigned)f2bf(v[2]) | ((unsigned)f2bf(v[3]) << 16);
            uint2 pk; pk.x = w0; pk.y = w1;
            *(uint2*)&At[row][c4 * 4] = pk;
        }
#pragma unroll
        for (int q = 0; q < 6; ++q) {
            int f = q * 256 + t;
            int colr = f >> 2, q8 = f & 3;
            const unsigned short* src = W1T + (size_t)(cb * 384 + colr) * K2 + k0 + q8 * 8;
            *(uint4*)&Bt[colr][q8 * 8] = *(const uint4*)src;
        }
        __syncthreads();

        bf16x8 af[4], bfr[6];
#pragma unroll
        for (int i = 0; i < 4; i++) af[i]  = *(const bf16x8*)&At[i * 16 + s][g * 8];
#pragma unroll
        for (int j = 0; j < 6; j++) bfr[j] = *(const bf16x8*)&Bt[wv * 96 + j * 16 + s][g * 8];
#pragma unroll
        for (int i = 0; i < 4; i++)
#pragma unroll
            for (int j = 0; j < 6; j++)
                acc[i][j] = __builtin_amdgcn_mfma_f32_16x16x32_bf16(af[i], bfr[j], acc[i][j], 0, 0, 0);
        __syncthreads();
    }

    float w2v[6], b1v[6];
#pragma unroll
    for (int j = 0; j < 6; j++) {
        int col = cb * 384 + wv * 96 + j * 16 + s;
        w2v[j] = W2[col];
        b1v[j] = b1[col];
    }
    float ssum[4][4];
#pragma unroll
    for (int i = 0; i < 4; i++)
#pragma unroll
        for (int r = 0; r < 4; r++) ssum[i][r] = 0.f;
#pragma unroll
    for (int i = 0; i < 4; i++)
#pragma unroll
        for (int j = 0; j < 6; j++)
#pragma unroll
            for (int r = 0; r < 4; r++) {
                float h = acc[i][j][r] + b1v[j];
                h = h > 0.f ? h : 0.f;
                ssum[i][r] = fmaf(h, w2v[j], ssum[i][r]);
            }
#pragma unroll
    for (int sft = 1; sft < 16; sft <<= 1)
#pragma unroll
        for (int i = 0; i < 4; i++)
#pragma unroll
            for (int r = 0; r < 4; r++) ssum[i][r] += __shfl_xor(ssum[i][r], sft);
    if (s == 0) {
#pragma unroll
        for (int i = 0; i < 4; i++)
#pragma unroll
            for (int r = 0; r < 4; r++)
                atomicAdd(&tokscore[tile * 64 + i * 16 + g * 4 + r], ssum[i][r]);
    }
}

// ---------------------------------------------------------------------------
// Kernel 4: masked row sums -> scores[512], dot_scores[512]
// ---------------------------------------------------------------------------
__global__ __launch_bounds__(128) void reduce_kernel(
        const float* __restrict__ inp,
        const float* __restrict__ tokscore,
        const float* __restrict__ dotmax,
        const float* __restrict__ b2,
        float* __restrict__ out)
{
    int p = blockIdx.x;
    int l = threadIdx.x;
    float c0  = inp[((size_t)(2 * p) * LTOK + l) * DDIM];
    float msk = (c0 != 0.0f) ? 1.f : 0.f;
    float sc  = (tokscore[p * LTOK + l] + b2[0]) * msk;
    float dm  = dotmax[p * LTOK + l] * msk;
#pragma unroll
    for (int sh = 1; sh < 64; sh <<= 1) {
        sc += __shfl_xor(sc, sh);
        dm += __shfl_xor(dm, sh);
    }
    __shared__ float tmp[4];
    if ((l & 63) == 0) { tmp[(l >> 6) * 2] = sc; tmp[(l >> 6) * 2 + 1] = dm; }
    __syncthreads();
    if (l == 0) {
        out[p]          = tmp[0] + tmp[2];
        out[NPAIR + p]  = tmp[1] + tmp[3];
    }
}

extern "C" void kernel_launch(void* const* d_in, const int* in_sizes, int n_in,
                              void* d_out, int out_size, void* d_ws, size_t ws_size,
                              hipStream_t stream)
{
    const float* inp = (const float*)d_in[0];
    const float* W1  = (const float*)d_in[1];
    const float* b1  = (const float*)d_in[2];
    const float* W2  = (const float*)d_in[3];
    const float* b2  = (const float*)d_in[4];
    float* out = (float*)d_out;

    char* ws = (char*)d_ws;
    unsigned short* W1T   = (unsigned short*)ws;                 // 2,359,296 B
    float*          dotmx = (float*)(ws + 2359296);              // 262,144 B
    int*            amax  = (int*)(ws + 2359296 + 262144);       // 262,144 B
    float*          toksc = (float*)(ws + 2359296 + 2*262144);   // 262,144 B
    unsigned short* Cbf   = (unsigned short*)(ws + 2359296 + 3*262144);
    unsigned short* Ebf   = Cbf + (size_t)NPAIR * LTOK * DDIM;   // +100,663,296 B each
    const size_t NEED = 2359296ull + 3ull*262144ull + 2ull*100663296ull;  // 204,472,320

    const bool big = ws_size >= NEED;

    hipMemsetAsync(toksc, 0, 65536 * sizeof(float), stream);
    w1t_kernel<<<(HDIM * K2 / 8 + 255) / 256, 256, 0, stream>>>(W1, W1T);
    if (big) {
        sim_max_kernel<true><<<dim3(NPAIR, 2), 256, 0, stream>>>(inp, dotmx, amax, Cbf, Ebf);
        mlp2_kernel<<<dim3(NPAIR, 3), 256, 0, stream>>>(Cbf, Ebf, W1T, b1, W2, amax, toksc);
    } else {
        sim_max_kernel<false><<<dim3(NPAIR, 2), 256, 0, stream>>>(inp, dotmx, amax, nullptr, nullptr);
        mlp_kernel<<<dim3(1024, 2), 256, 0, stream>>>(inp, W1T, b1, W2, amax, toksc);
    }
    reduce_kernel<<<NPAIR, 128, 0, stream>>>(inp, toksc, dotmx, b2, out);
}

// Round 5
// 324.033 us; speedup vs baseline: 1.4559x; 1.4559x over previous
//
#include <hip/hip_runtime.h>
#include <hip/hip_bf16.h>
#include <stdint.h>

// Problem constants
#define NPAIR 512      // B*C
#define LTOK  128      // L
#define DDIM  768      // D
#define HDIM  768      // H
#define K2    1536     // 2*D
#define MARGIN 0.4f    // bf16-sim uncertainty margin (~9 sigma of gap error)

typedef float f32x4 __attribute__((ext_vector_type(4)));
typedef short bf16x8 __attribute__((ext_vector_type(8)));

static __device__ __forceinline__ unsigned short f2bf(float f) {
    union { float f; uint32_t u; } v; v.f = f;
    uint32_t u = v.u;
    u += 0x7FFF + ((u >> 16) & 1);   // RNE
    return (unsigned short)(u >> 16);
}

static __device__ __forceinline__ uint2 pack4(f32x4 v) {
    uint2 r;
    r.x = (unsigned)f2bf(v[0]) | ((unsigned)f2bf(v[1]) << 16);
    r.y = (unsigned)f2bf(v[2]) | ((unsigned)f2bf(v[3]) << 16);
    return r;
}

typedef const __attribute__((address_space(1))) void* gas_t;
typedef __attribute__((address_space(3))) void* las_t;
static __device__ __forceinline__ void gld16(const void* g, void* l) {
    __builtin_amdgcn_global_load_lds((gas_t)g, (las_t)l, 16, 0, 0);
}

// exact fp32 dot over 768 elems, whole wave participates; all lanes return sum
// 64 lanes x 4 floats x 3 iters = 768 elements exactly.
static __device__ __forceinline__ float wave_dot(const float* __restrict__ a,
                                                 const float* __restrict__ b,
                                                 int lane) {
    f32x4 s4 = {0.f, 0.f, 0.f, 0.f};
#pragma unroll
    for (int it = 0; it < 3; ++it) {
        int k = it * 256 + lane * 4;
        f32x4 av = *(const f32x4*)(a + k);
        f32x4 bv = *(const f32x4*)(b + k);
#pragma unroll
        for (int q = 0; q < 4; ++q) s4[q] = fmaf(av[q], bv[q], s4[q]);
    }
    float v = (s4[0] + s4[1]) + (s4[2] + s4[3]);
#pragma unroll
    for (int m = 1; m < 64; m <<= 1) v += __shfl_xor(v, m);
    return v;
}

// ---------------------------------------------------------------------------
// Kernel 1: bf16-MFMA sim + top-2 margin + fused exact fp32 recheck.
// Grid (NPAIR), 256 threads = 4 waves. Wave wv: rows [wv*32, wv*32+32).
// Also emits bf16 copies of context/entity (Cbf/Ebf) for the MLP GEMM.
// ---------------------------------------------------------------------------
__global__ __launch_bounds__(256, 2) void simfma_kernel(
        const float* __restrict__ inp,
        float* __restrict__ dotmax, int* __restrict__ argmax,
        unsigned short* __restrict__ Cbf, unsigned short* __restrict__ Ebf)
{
    const int p    = blockIdx.x;
    const int t    = threadIdx.x;
    const int wv   = t >> 6;
    const int lane = t & 63;
    const int s    = lane & 15, g = lane >> 4;

    const float* Cbase = inp + (size_t)(2 * p) * LTOK * DDIM;
    const float* Ebase = Cbase + (size_t)LTOK * DDIM;

    __shared__ unsigned short Cl[2][128][32];   // 16 KB (2 k-halves of BK=64)
    __shared__ unsigned short El[2][128][32];   // 16 KB
    __shared__ unsigned short cand[128][16];    // 4 KB candidate col lists
    __shared__ int   ccnt[128];
    __shared__ float rm1[128];
    __shared__ int   ri1[128];

    if (t < 128) ccnt[t] = 0;

    f32x4 acc[2][8];
#pragma unroll
    for (int i = 0; i < 2; i++)
#pragma unroll
        for (int j = 0; j < 8; j++) acc[i][j] = (f32x4){0.f, 0.f, 0.f, 0.f};

    for (int kc = 0; kc < 12; ++kc) {
        const int k0 = kc * 64;
        // stage C: 128 rows x 64 k fp32 -> bf16 LDS + global WB. 8 f32x4/thread.
#pragma unroll
        for (int it = 0; it < 8; ++it) {
            int slot = it * 256 + t;
            int row = slot >> 4, l16 = slot & 15;
            int h = l16 >> 3, kl = (l16 & 7) * 4;
            f32x4 cv = *(const f32x4*)(Cbase + (size_t)row * DDIM + k0 + l16 * 4);
            uint2 cw = pack4(cv);
            *(uint2*)&Cl[h][row][kl] = cw;
            *(uint2*)(Cbf + ((size_t)p * LTOK + row) * DDIM + k0 + l16 * 4) = cw;
        }
        // stage E likewise
#pragma unroll
        for (int it = 0; it < 8; ++it) {
            int slot = it * 256 + t;
            int row = slot >> 4, l16 = slot & 15;
            int h = l16 >> 3, kl = (l16 & 7) * 4;
            f32x4 ev = *(const f32x4*)(Ebase + (size_t)row * DDIM + k0 + l16 * 4);
            uint2 ew = pack4(ev);
            *(uint2*)&El[h][row][kl] = ew;
            *(uint2*)(Ebf + ((size_t)p * LTOK + row) * DDIM + k0 + l16 * 4) = ew;
        }
        __syncthreads();

#pragma unroll
        for (int h = 0; h < 2; ++h) {
            bf16x8 af[2], bfr[8];
#pragma unroll
            for (int i = 0; i < 2; ++i)
                af[i] = *(const bf16x8*)&Cl[h][wv * 32 + i * 16 + s][g * 8];
#pragma unroll
            for (int j = 0; j < 8; ++j)
                bfr[j] = *(const bf16x8*)&El[h][j * 16 + s][g * 8];
#pragma unroll
            for (int i = 0; i < 2; ++i)
#pragma unroll
                for (int j = 0; j < 8; ++j)
                    acc[i][j] = __builtin_amdgcn_mfma_f32_16x16x32_bf16(af[i], bfr[j], acc[i][j], 0, 0, 0);
        }
        __syncthreads();
    }

    // top-2 (value,index / second-value) per row; row = wv*32 + i*16 + g*4 + r
#pragma unroll
    for (int i = 0; i < 2; ++i)
#pragma unroll
        for (int r = 0; r < 4; ++r) {
            float m1 = acc[i][0][r]; int i1 = s; float m2 = -1e30f;
#pragma unroll
            for (int j = 1; j < 8; ++j) {
                float v = acc[i][j][r]; int c = j * 16 + s;
                if (v > m1 || (v == m1 && c < i1)) { m2 = m1; m1 = v; i1 = c; }
                else if (v > m2) m2 = v;
            }
#pragma unroll
            for (int msk = 1; msk < 16; msk <<= 1) {
                float o1 = __shfl_xor(m1, msk);
                int   oi = __shfl_xor(i1, msk);
                float o2 = __shfl_xor(m2, msk);
                bool take = (o1 > m1) || (o1 == m1 && oi < i1);
                float nm2 = take ? fmaxf(m1, o2) : fmaxf(m2, o1);
                if (take) { m1 = o1; i1 = oi; }
                m2 = nm2;
            }
            int row = wv * 32 + i * 16 + g * 4 + r;
            if (s == 0) { rm1[row] = m1; ri1[row] = i1; }
            // candidate collection: cols within MARGIN of max (excluding argmax)
            float thr = m1 - MARGIN;
#pragma unroll
            for (int j = 0; j < 8; ++j) {
                float v = acc[i][j][r]; int c = j * 16 + s;
                if (v >= thr && c != i1) {
                    int idx = atomicAdd(&ccnt[row], 1);
                    if (idx < 16) cand[row][idx] = (unsigned short)c;
                }
            }
        }
    __syncthreads();

    // phase B: per row, either commit bf16 result or exact-fp32 recheck
    for (int rr = 0; rr < 32; ++rr) {
        int row = wv + rr * 4;
        int cnt = ccnt[row];
        float m1 = rm1[row]; int i1 = ri1[row];
        size_t ob = (size_t)p * LTOK + row;
        if (cnt == 0) {
            if (lane == 0) { dotmax[ob] = m1; argmax[ob] = i1; }
            continue;
        }
        const float* cr = Cbase + (size_t)row * DDIM;
        float bv; int bc;
        if (cnt <= 16) {
            bv = wave_dot(cr, Ebase + (size_t)i1 * DDIM, lane); bc = i1;
            for (int q = 0; q < cnt; ++q) {
                int c = cand[row][q];
                float v = wave_dot(cr, Ebase + (size_t)c * DDIM, lane);
                if (v > bv || (v == bv && c < bc)) { bv = v; bc = c; }
            }
        } else {   // overflow: recheck all cols (vanishingly rare)
            bv = -1e30f; bc = 0;
            for (int c = 0; c < 128; ++c) {
                float v = wave_dot(cr, Ebase + (size_t)c * DDIM, lane);
                if (v > bv || (v == bv && c < bc)) { bv = v; bc = c; }
            }
        }
        if (lane == 0) { dotmax[ob] = bv; argmax[ob] = bc; }
    }
}

// ---------------------------------------------------------------------------
// Kernel 2: W1 [1536,768] fp32 -> W1T [768][1536] bf16 (coalesced writes)
// ---------------------------------------------------------------------------
__global__ __launch_bounds__(256) void w1t_kernel(
        const float* __restrict__ W1, unsigned short* __restrict__ W1T)
{
    int idx = blockIdx.x * 256 + threadIdx.x;      // 147456 threads, 8 k each
    if (idx >= HDIM * K2 / 8) return;
    int c  = idx / (K2 / 8);
    int k0 = (idx % (K2 / 8)) * 8;
    unsigned short v[8];
#pragma unroll
    for (int q = 0; q < 8; q++) v[q] = f2bf(W1[(size_t)(k0 + q) * HDIM + c]);
    *(uint4*)(W1T + (size_t)c * K2 + k0) = *(const uint4*)v;
}

// ---------------------------------------------------------------------------
// Kernel 3: MFMA GEMM. Block = 1 pair (128 tokens) x 256 cols, grid (512, 3).
// 4 waves, wave tile 64x128, acc 4x8, BK=64 as 2x32-k panels.
// A (gathered, bf16) and B staged via global_load_lds width=16.
// ---------------------------------------------------------------------------
__global__ __launch_bounds__(256, 2) void mlp2_kernel(
        const unsigned short* __restrict__ Cbf,
        const unsigned short* __restrict__ Ebf,
        const unsigned short* __restrict__ W1T,
        const float* __restrict__ b1,
        const float* __restrict__ W2,
        const int* __restrict__ argmax,
        float* __restrict__ tokscore)
{
    const int p    = blockIdx.x;
    const int cbk  = blockIdx.y;           // 0..2, 256 cols each
    const int t    = threadIdx.x;
    const int wv   = t >> 6;
    const int lane = t & 63;
    const int s    = lane & 15, g = lane >> 4;
    const int wr   = wv >> 1, wc = wv & 1; // 64-row half, 128-col half

    __shared__ unsigned short Ald[2][128][32];   // 16 KB
    __shared__ unsigned short Bld[2][256][32];   // 32 KB
    __shared__ int am[128];

    if (t < 128) am[t] = argmax[p * LTOK + t];

    f32x4 acc[4][8];
#pragma unroll
    for (int i = 0; i < 4; i++)
#pragma unroll
        for (int j = 0; j < 8; j++) acc[i][j] = (f32x4){0.f, 0.f, 0.f, 0.f};

    const int rsub = lane >> 2;      // 0..15
    const int chk  = lane & 3;       // 16B chunk within 64B row

    for (int kc = 0; kc < 24; ++kc) {
        const int k0   = kc * 64;
        const bool ctx = (kc < 12);
        const int kloc = ctx ? k0 : (k0 - DDIM);

#pragma unroll
        for (int h = 0; h < 2; ++h)
#pragma unroll
            for (int n = 0; n < 4; ++n) {
                int c0  = (wv * 4 + n) * 16;
                int col = c0 + rsub;
                const unsigned short* src =
                    W1T + (size_t)(cbk * 256 + col) * K2 + k0 + h * 32 + chk * 8;
                gld16(src, &Bld[h][c0][0]);
            }
#pragma unroll
        for (int h = 0; h < 2; ++h)
#pragma unroll
            for (int n = 0; n < 2; ++n) {
                int r0 = (wv * 2 + n) * 16;
                int r  = r0 + rsub;
                const unsigned short* base = ctx
                    ? (Cbf + ((size_t)p * LTOK + r) * DDIM)
                    : (Ebf + ((size_t)p * LTOK + am[r]) * DDIM);
                gld16(base + kloc + h * 32 + chk * 8, &Ald[h][r0][0]);
            }
        __syncthreads();

#pragma unroll
        for (int h = 0; h < 2; ++h) {
            bf16x8 af[4], bfr[8];
#pragma unroll
            for (int i = 0; i < 4; ++i)
                af[i] = *(const bf16x8*)&Ald[h][wr * 64 + i * 16 + s][g * 8];
#pragma unroll
            for (int j = 0; j < 8; ++j)
                bfr[j] = *(const bf16x8*)&Bld[h][wc * 128 + j * 16 + s][g * 8];
#pragma unroll
            for (int i = 0; i < 4; ++i)
#pragma unroll
                for (int j = 0; j < 8; ++j)
                    acc[i][j] = __builtin_amdgcn_mfma_f32_16x16x32_bf16(af[i], bfr[j], acc[i][j], 0, 0, 0);
        }
        __syncthreads();
    }

    // epilogue: relu(acc + b1) . W2, reduce over 16 col-lanes, atomic per token
    float w2v[8], b1v[8];
#pragma unroll
    for (int j = 0; j < 8; j++) {
        int col = cbk * 256 + wc * 128 + j * 16 + s;
        w2v[j] = W2[col];
        b1v[j] = b1[col];
    }
    float ssum[4][4];
#pragma unroll
    for (int i = 0; i < 4; i++)
#pragma unroll
        for (int r = 0; r < 4; r++) ssum[i][r] = 0.f;
#pragma unroll
    for (int i = 0; i < 4; i++)
#pragma unroll
        for (int j = 0; j < 8; j++)
#pragma unroll
            for (int r = 0; r < 4; r++) {
                float h = acc[i][j][r] + b1v[j];
                h = h > 0.f ? h : 0.f;
                ssum[i][r] = fmaf(h, w2v[j], ssum[i][r]);
            }
#pragma unroll
    for (int sft = 1; sft < 16; sft <<= 1)
#pragma unroll
        for (int i = 0; i < 4; i++)
#pragma unroll
            for (int r = 0; r < 4; r++) ssum[i][r] += __shfl_xor(ssum[i][r], sft);
    if (s == 0) {
#pragma unroll
        for (int i = 0; i < 4; i++)
#pragma unroll
            for (int r = 0; r < 4; r++)
                atomicAdd(&tokscore[p * LTOK + wr * 64 + i * 16 + g * 4 + r], ssum[i][r]);
    }
}

// ---------------------------------------------------------------------------
// Fallback kernels (ws too small): fp32 sim + fused-gather MLP
// ---------------------------------------------------------------------------
__global__ __launch_bounds__(256) void sim_fp32_kernel(
        const float* __restrict__ inp,
        float* __restrict__ dotmax, int* __restrict__ argmax)
{
    const int p  = blockIdx.x;
    const int t  = threadIdx.x;
    const int tx = t & 15, ty = t >> 4;
    const float* Cbase = inp + (size_t)(2 * p) * LTOK * DDIM;
    const float* Ebase = Cbase + (size_t)LTOK * DDIM;

    __shared__ float Ct[128][36];
    __shared__ float Et[128][36];

    float acc[8][8];
#pragma unroll
    for (int i = 0; i < 8; i++)
#pragma unroll
        for (int j = 0; j < 8; j++) acc[i][j] = 0.f;

    for (int kc = 0; kc < 24; ++kc) {
        const int k0 = kc * 32;
#pragma unroll
        for (int q = 0; q < 4; ++q) {
            int f = q * 256 + t;
            int row = f >> 3, c4 = f & 7;
            *(f32x4*)&Ct[row][c4 * 4] = *(const f32x4*)(Cbase + (size_t)row * DDIM + k0 + c4 * 4);
            *(f32x4*)&Et[row][c4 * 4] = *(const f32x4*)(Ebase + (size_t)row * DDIM + k0 + c4 * 4);
        }
        __syncthreads();
#pragma unroll
        for (int kk4 = 0; kk4 < 8; ++kk4) {
            f32x4 cr[8], er[8];
#pragma unroll
            for (int i = 0; i < 8; i++) cr[i] = *(const f32x4*)&Ct[ty + 16 * i][kk4 * 4];
#pragma unroll
            for (int j = 0; j < 8; j++) er[j] = *(const f32x4*)&Et[tx + 16 * j][kk4 * 4];
#pragma unroll
            for (int kk = 0; kk < 4; kk++)
#pragma unroll
                for (int i = 0; i < 8; i++)
#pragma unroll
                    for (int j = 0; j < 8; j++)
                        acc[i][j] = fmaf(cr[i][kk], er[j][kk], acc[i][j]);
        }
        __syncthreads();
    }
#pragma unroll
    for (int i = 0; i < 8; i++) {
        float m = acc[i][0]; int mi = tx;
#pragma unroll
        for (int j = 1; j < 8; j++) {
            int c = tx + 16 * j;
            float v = acc[i][j];
            if (v > m || (v == m && c < mi)) { m = v; mi = c; }
        }
#pragma unroll
        for (int sft = 1; sft < 16; sft <<= 1) {
            float vo = __shfl_xor(m, sft);
            int   io = __shfl_xor(mi, sft);
            if (vo > m || (vo == m && io < mi)) { m = vo; mi = io; }
        }
        if (tx == 0) {
            int r = ty + 16 * i;
            dotmax[(size_t)p * LTOK + r] = m;
            argmax[(size_t)p * LTOK + r] = mi;
        }
    }
}

__global__ __launch_bounds__(256, 2) void mlp_kernel(
        const float* __restrict__ inp,
        const unsigned short* __restrict__ W1T,
        const float* __restrict__ b1,
        const float* __restrict__ W2,
        const int* __restrict__ argmax,
        float* __restrict__ tokscore)
{
    const int tile = blockIdx.x;
    const int cb   = blockIdx.y;
    const int t    = threadIdx.x;
    const int wv   = t >> 6;
    const int lane = t & 63;
    const int s    = lane & 15, g = lane >> 4;

    __shared__ unsigned short At[64][32];
    __shared__ unsigned short Bt[384][32];
    __shared__ int am[64];

    if (t < 64) am[t] = argmax[tile * 64 + t];
    __syncthreads();

    f32x4 acc[4][6];
#pragma unroll
    for (int i = 0; i < 4; i++)
#pragma unroll
        for (int j = 0; j < 6; j++) acc[i][j] = (f32x4){0.f, 0.f, 0.f, 0.f};

    for (int kc = 0; kc < 48; ++kc) {
        const int k0  = kc * 32;
        const int sel = (kc >= 24) ? 1 : 0;
        const int kloc = k0 - sel * DDIM;
#pragma unroll
        for (int q = 0; q < 2; ++q) {
            int f = q * 256 + t;
            int row = f >> 3, c4 = f & 7;
            int token = tile * 64 + row;
            int pp = token >> 7;
            int lsel = sel ? am[row] : (token & 127);
            const float* src = inp + ((size_t)(2 * pp + sel) * LTOK + lsel) * DDIM + kloc + c4 * 4;
            f32x4 v = *(const f32x4*)src;
            uint2 pk = pack4(v);
            *(uint2*)&At[row][c4 * 4] = pk;
        }
#pragma unroll
        for (int q = 0; q < 6; ++q) {
            int f = q * 256 + t;
            int colr = f >> 2, q8 = f & 3;
            const unsigned short* src = W1T + (size_t)(cb * 384 + colr) * K2 + k0 + q8 * 8;
            *(uint4*)&Bt[colr][q8 * 8] = *(const uint4*)src;
        }
        __syncthreads();

        bf16x8 af[4], bfr[6];
#pragma unroll
        for (int i = 0; i < 4; i++) af[i]  = *(const bf16x8*)&At[i * 16 + s][g * 8];
#pragma unroll
        for (int j = 0; j < 6; j++) bfr[j] = *(const bf16x8*)&Bt[wv * 96 + j * 16 + s][g * 8];
#pragma unroll
        for (int i = 0; i < 4; i++)
#pragma unroll
            for (int j = 0; j < 6; j++)
                acc[i][j] = __builtin_amdgcn_mfma_f32_16x16x32_bf16(af[i], bfr[j], acc[i][j], 0, 0, 0);
        __syncthreads();
    }

    float w2v[6], b1v[6];
#pragma unroll
    for (int j = 0; j < 6; j++) {
        int col = cb * 384 + wv * 96 + j * 16 + s;
        w2v[j] = W2[col];
        b1v[j] = b1[col];
    }
    float ssum[4][4];
#pragma unroll
    for (int i = 0; i < 4; i++)
#pragma unroll
        for (int r = 0; r < 4; r++) ssum[i][r] = 0.f;
#pragma unroll
    for (int i = 0; i < 4; i++)
#pragma unroll
        for (int j = 0; j < 6; j++)
#pragma unroll
            for (int r = 0; r < 4; r++) {
                float h = acc[i][j][r] + b1v[j];
                h = h > 0.f ? h : 0.f;
                ssum[i][r] = fmaf(h, w2v[j], ssum[i][r]);
            }
#pragma unroll
    for (int sft = 1; sft < 16; sft <<= 1)
#pragma unroll
        for (int i = 0; i < 4; i++)
#pragma unroll
            for (int r = 0; r < 4; r++) ssum[i][r] += __shfl_xor(ssum[i][r], sft);
    if (s == 0) {
#pragma unroll
        for (int i = 0; i < 4; i++)
#pragma unroll
            for (int r = 0; r < 4; r++)
                atomicAdd(&tokscore[tile * 64 + i * 16 + g * 4 + r], ssum[i][r]);
    }
}

// ---------------------------------------------------------------------------
// Kernel 4: masked row sums -> scores[512], dot_scores[512]
// ---------------------------------------------------------------------------
__global__ __launch_bounds__(128) void reduce_kernel(
        const float* __restrict__ inp,
        const float* __restrict__ tokscore,
        const float* __restrict__ dotmax,
        const float* __restrict__ b2,
        float* __restrict__ out)
{
    int p = blockIdx.x;
    int l = threadIdx.x;
    float c0  = inp[((size_t)(2 * p) * LTOK + l) * DDIM];
    float msk = (c0 != 0.0f) ? 1.f : 0.f;
    float sc  = (tokscore[p * LTOK + l] + b2[0]) * msk;
    float dm  = dotmax[p * LTOK + l] * msk;
#pragma unroll
    for (int sh = 1; sh < 64; sh <<= 1) {
        sc += __shfl_xor(sc, sh);
        dm += __shfl_xor(dm, sh);
    }
    __shared__ float tmp[4];
    if ((l & 63) == 0) { tmp[(l >> 6) * 2] = sc; tmp[(l >> 6) * 2 + 1] = dm; }
    __syncthreads();
    if (l == 0) {
        out[p]          = tmp[0] + tmp[2];
        out[NPAIR + p]  = tmp[1] + tmp[3];
    }
}

extern "C" void kernel_launch(void* const* d_in, const int* in_sizes, int n_in,
                              void* d_out, int out_size, void* d_ws, size_t ws_size,
                              hipStream_t stream)
{
    const float* inp = (const float*)d_in[0];
    const float* W1  = (const float*)d_in[1];
    const float* b1  = (const float*)d_in[2];
    const float* W2  = (const float*)d_in[3];
    const float* b2  = (const float*)d_in[4];
    float* out = (float*)d_out;

    char* ws = (char*)d_ws;
    unsigned short* W1T   = (unsigned short*)ws;                 // 2,359,296 B
    float*          dotmx = (float*)(ws + 2359296);              // 262,144 B
    int*            amax  = (int*)(ws + 2359296 + 262144);       // 262,144 B
    float*          toksc = (float*)(ws + 2359296 + 2*262144);   // 262,144 B
    unsigned short* Cbf   = (unsigned short*)(ws + 2359296 + 3*262144);
    unsigned short* Ebf   = Cbf + (size_t)NPAIR * LTOK * DDIM;   // +100,663,296 B each
    const size_t NEED = 2359296ull + 3ull*262144ull + 2ull*100663296ull;  // 204,472,320

    const bool big = ws_size >= NEED;

    hipMemsetAsync(toksc, 0, 65536 * sizeof(float), stream);
    w1t_kernel<<<(HDIM * K2 / 8 + 255) / 256, 256, 0, stream>>>(W1, W1T);
    if (big) {
        simfma_kernel<<<NPAIR, 256, 0, stream>>>(inp, dotmx, amax, Cbf, Ebf);
        mlp2_kernel<<<dim3(NPAIR, 3), 256, 0, stream>>>(Cbf, Ebf, W1T, b1, W2, amax, toksc);
    } else {
        sim_fp32_kernel<<<NPAIR, 256, 0, stream>>>(inp, dotmx, amax);
        mlp_kernel<<<dim3(1024, 2), 256, 0, stream>>>(inp, W1T, b1, W2, amax, toksc);
    }
    reduce_kernel<<<NPAIR, 128, 0, stream>>>(inp, toksc, dotmx, b2, out);
}